// Round 6
// baseline (678.235 us; speedup 1.0000x reference)
//
#include <hip/hip_runtime.h>

typedef __attribute__((ext_vector_type(8))) short bf16x8;
typedef __attribute__((ext_vector_type(4))) float f32x4;
typedef __attribute__((ext_vector_type(2))) float f32x2;

#define NBUK 196      // src>>9 for src<100352
#define BSTR 32       // bin/cursor padding: one 128B line per counter

__device__ __forceinline__ float leaky(float v) { return fmaxf(v, 0.01f * v); }

__device__ __forceinline__ unsigned short f2bf(float a) {
    unsigned int u = __float_as_uint(a);
    return (unsigned short)((u + 0x7FFFu + ((u >> 16) & 1u)) >> 16);
}

__device__ __forceinline__ unsigned int cvtpk(float a, float b) {
#if __has_builtin(__builtin_amdgcn_cvt_pk_bf16_f32)
    typedef __attribute__((ext_vector_type(2))) __bf16 bf2_t;
    bf2_t v = __builtin_amdgcn_cvt_pk_bf16_f32(a, b);
    return __builtin_bit_cast(unsigned int, v);
#else
    unsigned int ua = __float_as_uint(a);
    ua = (ua + 0x7FFFu + ((ua >> 16) & 1u)) >> 16;
    unsigned int ub = __float_as_uint(b);
    ub = (ub + 0x7FFFu + ((ub >> 16) & 1u)) >> 16;
    return ua | (ub << 16);
#endif
}

__device__ __forceinline__ f32x2 unpk2(unsigned int d) {
    f32x2 r;
    r.x = __uint_as_float(d << 16);
    r.y = __uint_as_float(d & 0xFFFF0000u);
    return r;
}

__device__ __forceinline__ unsigned int mix1(unsigned int u, unsigned int i) {
    f32x2 v = unpk2(u) + unpk2(i);
    v = __builtin_elementwise_max(v, v * 0.01f);
    return cvtpk(v.x, v.y);
}

// Weight prep (unchanged layouts) + zero the sort bins (block 0; hist runs
// after prep in stream order, so no race).
__global__ __launch_bounds__(128) void prep(const float* __restrict__ WL,
                                            const float* __restrict__ WR,
                                            const float* __restrict__ W1,
                                            unsigned short* __restrict__ WLf,
                                            unsigned short* __restrict__ WRf,
                                            unsigned short* __restrict__ Wf,
                                            int* __restrict__ bins) {
    int g = blockIdx.x;
    int t = threadIdx.x;
    if (g == 0) {
        if (t < NBUK) bins[t * BSTR] = 0;
        if (t + 128 < NBUK) bins[(t + 128) * BSTR] = 0;
    }
    int f = (g & 127) * 128 + t;
    int j = f & 7, lane = (f >> 3) & 63, nt = (f >> 9) & 7, kb = f >> 12;
    int n = nt * 16 + (lane & 15);
    int kf = kb * 32 + (lane >> 4) * 8 + j;
    if (g < 128) {
        WLf[f] = f2bf(WL[kf * 128 + n]);
    } else if (g < 256) {
        WRf[f] = f2bf(WR[kf * 128 + n]);
    } else {
        int k = (kf & 7) * 16 + (kf >> 3);  // phi
        Wf[f] = f2bf(W1[k * 128 + n]);
    }
}

// LDS-preaggregated histogram of src>>9 (padded global bins: one line each).
__global__ __launch_bounds__(256) void hist(const int* __restrict__ src,
                                            int* __restrict__ bins, int E) {
    __shared__ int lb[NBUK];
    int t = threadIdx.x;
    if (t < NBUK) lb[t] = 0;
    __syncthreads();
    for (int e = blockIdx.x * 256 + t; e < E; e += gridDim.x * 256)
        atomicAdd(&lb[src[e] >> 9], 1);
    __syncthreads();
    if (t < NBUK && lb[t]) atomicAdd(&bins[t * BSTR], lb[t]);
}

// Exclusive scan of 196 bins -> base[] (compact) and cur[] (padded cursors).
__global__ __launch_bounds__(256) void scan196(const int* __restrict__ bins,
                                               int* __restrict__ base,
                                               int* __restrict__ cur) {
    __shared__ int sc[256];
    int t = threadIdx.x;
    int v = (t < NBUK) ? bins[t * BSTR] : 0;
    sc[t] = v;
    __syncthreads();
    for (int off = 1; off < 256; off <<= 1) {
        int x = (t >= off) ? sc[t - off] : 0;
        __syncthreads();
        sc[t] += x;
        __syncthreads();
    }
    if (t < NBUK) {
        int ex = sc[t] - v;
        base[t] = ex;
        cur[t * BSTR] = ex;
    }
}

// Exact scatter into packed bucket regions (atomic cursors start at base).
// Bucket fill order is race-dependent, but each edge's result is computed
// identically and stored to out[pe[slot]] exactly once -> bit-deterministic.
__global__ __launch_bounds__(256) void scatter(const int* __restrict__ src,
                                               const int* __restrict__ dst,
                                               int* __restrict__ cur,
                                               int* __restrict__ sb,
                                               int* __restrict__ db,
                                               int* __restrict__ pe, int E) {
    for (int e = blockIdx.x * 256 + threadIdx.x; e < E; e += gridDim.x * 256) {
        int s_ = src[e], d_ = dst[e];
        int slot = atomicAdd(&cur[(s_ >> 9) * BSTR], 1);
        sb[slot] = s_;
        db[slot] = d_;
        pe[slot] = e;
    }
}

#define PITCH 136  // bf16 elems per LDS row (272 B -> row-to-row bank shift 4)

// Node linears (v3: LDS epilogue at pitch 136, coalesced 64B flush). ~34us.
__global__ __launch_bounds__(512, 6) void node_mfma2(const float* __restrict__ h_user,
                                                     const float* __restrict__ h_item,
                                                     const unsigned short* __restrict__ WLf,
                                                     const unsigned short* __restrict__ WRf,
                                                     const float* __restrict__ b_left,
                                                     const float* __restrict__ b_right,
                                                     unsigned short* __restrict__ u_f,
                                                     unsigned short* __restrict__ i_f,
                                                     int N_U, int N_I, int BU) {
    bool isU = (int)blockIdx.x < BU;
    const float* h = isU ? h_user : h_item;
    const unsigned short* Wfr = isU ? WLf : WRf;
    const float* b = isU ? b_left : b_right;
    unsigned short* out = isU ? u_f : i_f;
    int N = isU ? N_U : N_I;
    int r0 = (isU ? blockIdx.x : blockIdx.x - BU) * 128;

    __shared__ __attribute__((aligned(16))) unsigned short xt[128 * PITCH];
    int t = threadIdx.x;
    int s = t & 31;
    int el0 = t >> 5;

    f32x4 g[8];
#pragma unroll
    for (int pass = 0; pass < 8; ++pass) {
        int row = min(r0 + pass * 16 + el0, N - 1);
        g[pass] = *(const f32x4*)(h + (size_t)row * 128 + s * 4);
    }
#pragma unroll
    for (int pass = 0; pass < 8; ++pass) {
        int el = pass * 16 + el0;
        unsigned int* rp = (unsigned int*)(xt + el * PITCH + s * 4);
        rp[0] = cvtpk(g[pass].x, g[pass].y);
        rp[1] = cvtpk(g[pass].z, g[pass].w);
    }
    __syncthreads();

    int wave = t >> 6;
    int lane = t & 63;
    int col = lane & 15;
    int quad = lane >> 4;
    int wp = wave >> 1;
    int ch = wave & 1;
    int m0 = wp * 32;

    f32x4 acc[2][4];
#pragma unroll
    for (int mt = 0; mt < 2; ++mt)
#pragma unroll
        for (int i = 0; i < 4; ++i) acc[mt][i] = (f32x4){0.f, 0.f, 0.f, 0.f};

#pragma unroll
    for (int kb = 0; kb < 4; ++kb) {
        bf16x8 afr[2];
#pragma unroll
        for (int mt = 0; mt < 2; ++mt)
            afr[mt] = *(const bf16x8*)(xt + (m0 + mt * 16 + col) * PITCH + kb * 32 + quad * 8);
#pragma unroll
        for (int i = 0; i < 4; ++i) {
            int nt = ch * 4 + i;
            bf16x8 bfr = *(const bf16x8*)(Wfr + ((kb * 8 + nt) * 64 + lane) * 8);
            acc[0][i] = __builtin_amdgcn_mfma_f32_16x16x32_bf16(afr[0], bfr, acc[0][i], 0, 0, 0);
            acc[1][i] = __builtin_amdgcn_mfma_f32_16x16x32_bf16(afr[1], bfr, acc[1][i], 0, 0, 0);
        }
    }

    float bb[4];
#pragma unroll
    for (int i = 0; i < 4; ++i) bb[i] = b[(ch * 4 + i) * 16 + col];

    __syncthreads();

#pragma unroll
    for (int mt = 0; mt < 2; ++mt)
#pragma unroll
        for (int rr = 0; rr < 4; ++rr) {
            int row = m0 + mt * 16 + quad * 4 + rr;
            uint2 v;
            v.x = cvtpk(acc[mt][0][rr] + bb[0], acc[mt][1][rr] + bb[1]);
            v.y = cvtpk(acc[mt][2][rr] + bb[2], acc[mt][3][rr] + bb[3]);
            *(uint2*)(xt + (size_t)row * PITCH + col * 8 + ch * 4) = v;
        }
    __syncthreads();

    {
        int row = t >> 2;
        int seg = t & 3;
        if (r0 + row < N) {
            const uint4* lp = (const uint4*)(xt + (size_t)row * PITCH + seg * 32);
            uint4* gp = (uint4*)(out + (size_t)(r0 + row) * 128 + seg * 32);
            uint4 a0 = lp[0], a1 = lp[1], a2 = lp[2], a3 = lp[3];
            gp[0] = a0; gp[1] = a1; gp[2] = a2; gp[3] = a3;
        }
    }
}

// Bucketed edge kernel. Theory (r0-r5): edge time == FETCH/2.3TB/s; the
// 226MB FETCH vs 38.4MB unique features is per-XCD compulsory misses (each
// of 8 private L2s re-fetches the randomly-accessed feature set). Fix:
// edges pre-sorted into 196 buckets by src>>9 (512 users = 128KB of u_f),
// and bucket b's tiles pinned to XCD b%8 via blockIdx%8 mapping, so each
// u-row is fetched into exactly one L2 and reused ~10x.
// Physical block p: x=p&7 (XCD), q=p>>3, j=q/48, t0=q%48; bucket b=x+8j;
// tiles tt=t0,t0+48,... while tt*128<cnt (runtime loop -> no unroll/spill).
// Inner tile = r0's proven form (transient gathers, 2 barriers) + bias-init.
#define TE 128

__global__ __launch_bounds__(512, 6) void edge_kernel(
    const unsigned short* __restrict__ u_f, const unsigned short* __restrict__ i_f,
    const int* __restrict__ sb, const int* __restrict__ db,
    const int* __restrict__ pe,
    const int* __restrict__ bins, const int* __restrict__ base,
    const unsigned short* __restrict__ Wf,
    const float* __restrict__ b1, const float* __restrict__ W2,
    const float* __restrict__ b2, float* __restrict__ out, int E) {
    int p = blockIdx.x;
    int x = p & 7;
    int q = p >> 3;
    int j = q / 48;
    int t0 = q % 48;
    int b = x + (j << 3);
    if (b >= NBUK) return;
    int cnt = bins[b * BSTR];
    if (cnt == 0) return;
    int bs = base[b];

    __shared__ unsigned short xt[TE * PITCH];
    __shared__ float zb[4][2][32];
    int t = threadIdx.x;
    int s = t & 15;
    int el0 = t >> 4;  // 0..31

    int wave = t >> 6;
    int lane = t & 63;
    int col = lane & 15;
    int quad = lane >> 4;
    int wp = wave >> 1;
    int ch = wave & 1;
    int m0 = wp * 32;

    float bb[4], ww[4];
#pragma unroll
    for (int i = 0; i < 4; ++i) {
        int n = (ch * 4 + i) * 16 + col;
        bb[i] = b1[n];
        ww[i] = W2[n];
    }
    float b2v = b2[0];

    for (int tt = t0; tt * TE < cnt; tt += 48) {
        int s0 = tt * TE;

        // ---- stage: window 1 = 8 index loads, window 2 = 8 gathers ----
        int su[4], sd[4];
#pragma unroll
        for (int pass = 0; pass < 4; ++pass) {
            int sc = bs + min(s0 + pass * 32 + el0, cnt - 1);
            su[pass] = sb[sc];
            sd[pass] = db[sc];
        }
        {
            uint4 ug[4], ig[4];
#pragma unroll
            for (int pass = 0; pass < 4; ++pass) {
                ug[pass] = *(const uint4*)(u_f + (size_t)su[pass] * 128 + s * 8);
                ig[pass] = *(const uint4*)(i_f + (size_t)sd[pass] * 128 + s * 8);
            }
#pragma unroll
            for (int pass = 0; pass < 4; ++pass) {
                uint4 a;
                a.x = mix1(ug[pass].x, ig[pass].x);
                a.y = mix1(ug[pass].y, ig[pass].y);
                a.z = mix1(ug[pass].z, ig[pass].z);
                a.w = mix1(ug[pass].w, ig[pass].w);
                *(uint4*)(xt + (pass * 32 + el0) * PITCH + s * 8) = a;
            }
        }
        __syncthreads();  // (A) xt ready; also orders prev-tile zb reads
                          //     before this tile's zb writes

        // ---- MFMA: acc starts at b1 ----
        f32x4 acc[2][4];
#pragma unroll
        for (int mt = 0; mt < 2; ++mt)
#pragma unroll
            for (int i = 0; i < 4; ++i)
                acc[mt][i] = (f32x4){bb[i], bb[i], bb[i], bb[i]};

#pragma unroll
        for (int kb = 0; kb < 4; ++kb) {
            bf16x8 afr[2];
#pragma unroll
            for (int mt = 0; mt < 2; ++mt)
                afr[mt] = *(const bf16x8*)(xt + (m0 + mt * 16 + col) * PITCH + kb * 32 + quad * 8);
#pragma unroll
            for (int i = 0; i < 4; ++i) {
                int nt = ch * 4 + i;
                bf16x8 bfr = *(const bf16x8*)(Wf + ((kb * 8 + nt) * 64 + lane) * 8);
                acc[0][i] = __builtin_amdgcn_mfma_f32_16x16x32_bf16(afr[0], bfr, acc[0][i], 0, 0, 0);
                acc[1][i] = __builtin_amdgcn_mfma_f32_16x16x32_bf16(afr[1], bfr, acc[1][i], 0, 0, 0);
            }
        }

        // ---- epilogue: leaky + W2 dot + cross-lane reduce ----
        f32x4 pz[2];
#pragma unroll
        for (int mt = 0; mt < 2; ++mt) pz[mt] = (f32x4){0.f, 0.f, 0.f, 0.f};

#pragma unroll
        for (int i = 0; i < 4; ++i) {
#pragma unroll
            for (int mt = 0; mt < 2; ++mt) {
                f32x4 y = acc[mt][i];
                y = __builtin_elementwise_max(y, y * 0.01f);
                pz[mt] += y * ww[i];
            }
        }
#pragma unroll
        for (int off = 1; off < 16; off <<= 1)
#pragma unroll
            for (int mt = 0; mt < 2; ++mt)
#pragma unroll
                for (int rr = 0; rr < 4; ++rr) pz[mt][rr] += __shfl_xor(pz[mt][rr], off, 64);

        if (col == 0) {
#pragma unroll
            for (int mt = 0; mt < 2; ++mt)
#pragma unroll
                for (int rr = 0; rr < 4; ++rr)
                    zb[wp][ch][mt * 16 + quad * 4 + rr] = pz[mt][rr];
        }
        __syncthreads();  // (B) zb ready; xt reads complete

        // ---- store via original edge id (scattered 4B; out region is
        //      small, lines accumulate in L2) ----
        if (t < 128) {
            int sl = s0 + t;
            if (sl < cnt) {
                int g2 = t >> 5;
                int idx = t & 31;
                float z = zb[g2][0][idx] + zb[g2][1][idx] + b2v;
                out[pe[bs + sl]] = leaky(z);
            }
        }
        // next iteration's stage-writes to xt are ordered after barrier (B);
        // its zb writes are ordered after next barrier (A).
    }
}

extern "C" void kernel_launch(void* const* d_in, const int* in_sizes, int n_in,
                              void* d_out, int out_size, void* d_ws, size_t ws_size,
                              hipStream_t stream) {
    const float* h_user  = (const float*)d_in[0];
    const float* h_item  = (const float*)d_in[1];
    const int*   src_idx = (const int*)d_in[2];
    const int*   dst_idx = (const int*)d_in[3];
    const float* W_left  = (const float*)d_in[4];
    const float* b_left  = (const float*)d_in[5];
    const float* W_right = (const float*)d_in[6];
    const float* b_right = (const float*)d_in[7];
    const float* W1      = (const float*)d_in[8];
    const float* b1      = (const float*)d_in[9];
    const float* W2      = (const float*)d_in[10];
    const float* b2      = (const float*)d_in[11];
    float* out = (float*)d_out;

    int N_U = in_sizes[0] / 128;
    int N_I = in_sizes[1] / 128;
    int E   = in_sizes[2];

    // Workspace: [Wf 32KB][WLf 32KB][WRf 32KB][pad to 128KB]
    //            [u_f bf16][i_f bf16][4KB-aligned: bins|base|cur|sb|db|pe]
    unsigned short* Wf  = (unsigned short*)d_ws;
    unsigned short* WLf = Wf + 16384;
    unsigned short* WRf = WLf + 16384;
    unsigned short* u_f = (unsigned short*)((char*)d_ws + 131072);
    unsigned short* i_f = u_f + (size_t)N_U * 128;
    size_t mo = (131072 + (size_t)(N_U + N_I) * 256 + 4095) & ~(size_t)4095;
    int* bins = (int*)((char*)d_ws + mo);            // NBUK*BSTR ints (25KB, pad 32KB)
    int* base = (int*)((char*)d_ws + mo + 32768);    // NBUK ints (pad 4KB)
    int* cur  = (int*)((char*)d_ws + mo + 36864);    // NBUK*BSTR ints (pad 32KB)
    int* sb   = (int*)((char*)d_ws + mo + 69632);
    int* db   = sb + E;
    int* pe   = db + E;

    prep<<<384, 128, 0, stream>>>(W_left, W_right, W1, WLf, WRf, Wf, bins);

    hist<<<256, 256, 0, stream>>>(src_idx, bins, E);
    scan196<<<1, 256, 0, stream>>>(bins, base, cur);
    scatter<<<1024, 256, 0, stream>>>(src_idx, dst_idx, cur, sb, db, pe, E);

    int BU = (N_U + 127) / 128;
    int BI = (N_I + 127) / 128;
    node_mfma2<<<BU + BI, 512, 0, stream>>>(h_user, h_item, WLf, WRf, b_left, b_right,
                                            u_f, i_f, N_U, N_I, BU);

    // 8 XCDs x 25 bucket-slots x 48 tile-slots
    edge_kernel<<<9600, 512, 0, stream>>>(u_f, i_f, sb, db, pe, bins, base,
                                          Wf, b1, W2, b2, out, E);
}

// Round 7
// 227.402 us; speedup vs baseline: 2.9825x; 2.9825x over previous
//
#include <hip/hip_runtime.h>

typedef __attribute__((ext_vector_type(8))) short bf16x8;
typedef __attribute__((ext_vector_type(4))) float f32x4;
typedef __attribute__((ext_vector_type(2))) float f32x2;

__device__ __forceinline__ float leaky(float v) { return fmaxf(v, 0.01f * v); }

__device__ __forceinline__ unsigned short f2bf(float a) {
    unsigned int u = __float_as_uint(a);
    return (unsigned short)((u + 0x7FFFu + ((u >> 16) & 1u)) >> 16);
}

// RNE pack of two floats -> packed bf16x2 (HW v_cvt_pk_bf16_f32 when available)
__device__ __forceinline__ unsigned int cvtpk(float a, float b) {
#if __has_builtin(__builtin_amdgcn_cvt_pk_bf16_f32)
    typedef __attribute__((ext_vector_type(2))) __bf16 bf2_t;
    bf2_t v = __builtin_amdgcn_cvt_pk_bf16_f32(a, b);
    return __builtin_bit_cast(unsigned int, v);
#else
    unsigned int ua = __float_as_uint(a);
    ua = (ua + 0x7FFFu + ((ua >> 16) & 1u)) >> 16;
    unsigned int ub = __float_as_uint(b);
    ub = (ub + 0x7FFFu + ((ub >> 16) & 1u)) >> 16;
    return ua | (ub << 16);
#endif
}

// dword of 2 bf16 -> f32x2 (2 VALU ops)
__device__ __forceinline__ f32x2 unpk2(unsigned int d) {
    f32x2 r;
    r.x = __uint_as_float(d << 16);
    r.y = __uint_as_float(d & 0xFFFF0000u);
    return r;
}

// add + leaky + pack for one dword-pair of bf16
__device__ __forceinline__ unsigned int mix1(unsigned int u, unsigned int i) {
    f32x2 v = unpk2(u) + unpk2(i);
    v = __builtin_elementwise_max(v, v * 0.01f);
    return cvtpk(v.x, v.y);
}

// Weight prep, all in MFMA B-fragment order:
//   frag index f: j=f&7, lane=(f>>3)&63, nt=(f>>9)&7, kb=f>>12
//   n = nt*16 + (lane&15), k_frag = kb*32 + (lane>>4)*8 + j
// blocks [0,128):   WLf[f] = bf16(W_left[k_frag][n])
// blocks [128,256): WRf[f] = bf16(W_right[k_frag][n])
// blocks [256,384): Wf[f]  = bf16(W1[phi(k_frag)][n]), phi(p) = (p&7)*16 + (p>>3)
__global__ __launch_bounds__(128) void prep(const float* __restrict__ WL,
                                            const float* __restrict__ WR,
                                            const float* __restrict__ W1,
                                            unsigned short* __restrict__ WLf,
                                            unsigned short* __restrict__ WRf,
                                            unsigned short* __restrict__ Wf) {
    int g = blockIdx.x;
    int f = (g & 127) * 128 + threadIdx.x;
    int j = f & 7, lane = (f >> 3) & 63, nt = (f >> 9) & 7, kb = f >> 12;
    int n = nt * 16 + (lane & 15);
    int kf = kb * 32 + (lane >> 4) * 8 + j;
    if (g < 128) {
        WLf[f] = f2bf(WL[kf * 128 + n]);
    } else if (g < 256) {
        WRf[f] = f2bf(WR[kf * 128 + n]);
    } else {
        int k = (kf & 7) * 16 + (kf >> 3);  // phi
        Wf[f] = f2bf(W1[k * 128 + n]);
    }
}

#define PITCH 136  // bf16 elems per LDS row (272 B -> row-to-row bank shift 4)

// Node linears: out = bf16(h @ W + b), phi-order. v3 epilogue: fragments ->
// LDS at pitch 136 (flush read ~2-way conflict = free), coalesced 64B flush.
// Measured ~34us (ledger r5). Session model: timed loop = 2x256MiB harness
// fills (~82us, untouchable) + prep ~4 + node ~34 + edge ~100 + gaps ~6.
__global__ __launch_bounds__(512, 6) void node_mfma2(const float* __restrict__ h_user,
                                                     const float* __restrict__ h_item,
                                                     const unsigned short* __restrict__ WLf,
                                                     const unsigned short* __restrict__ WRf,
                                                     const float* __restrict__ b_left,
                                                     const float* __restrict__ b_right,
                                                     unsigned short* __restrict__ u_f,
                                                     unsigned short* __restrict__ i_f,
                                                     int N_U, int N_I, int BU) {
    bool isU = (int)blockIdx.x < BU;
    const float* h = isU ? h_user : h_item;
    const unsigned short* Wfr = isU ? WLf : WRf;
    const float* b = isU ? b_left : b_right;
    unsigned short* out = isU ? u_f : i_f;
    int N = isU ? N_U : N_I;
    int r0 = (isU ? blockIdx.x : blockIdx.x - BU) * 128;

    __shared__ __attribute__((aligned(16))) unsigned short xt[128 * PITCH];
    int t = threadIdx.x;
    int s = t & 31;
    int el0 = t >> 5;

    f32x4 g[8];
#pragma unroll
    for (int pass = 0; pass < 8; ++pass) {
        int row = min(r0 + pass * 16 + el0, N - 1);
        g[pass] = *(const f32x4*)(h + (size_t)row * 128 + s * 4);
    }
#pragma unroll
    for (int pass = 0; pass < 8; ++pass) {
        int el = pass * 16 + el0;
        unsigned int* rp = (unsigned int*)(xt + el * PITCH + s * 4);
        rp[0] = cvtpk(g[pass].x, g[pass].y);
        rp[1] = cvtpk(g[pass].z, g[pass].w);
    }
    __syncthreads();

    int wave = t >> 6;
    int lane = t & 63;
    int col = lane & 15;
    int quad = lane >> 4;
    int wp = wave >> 1;
    int ch = wave & 1;
    int m0 = wp * 32;

    f32x4 acc[2][4];
#pragma unroll
    for (int mt = 0; mt < 2; ++mt)
#pragma unroll
        for (int i = 0; i < 4; ++i) acc[mt][i] = (f32x4){0.f, 0.f, 0.f, 0.f};

#pragma unroll
    for (int kb = 0; kb < 4; ++kb) {
        bf16x8 afr[2];
#pragma unroll
        for (int mt = 0; mt < 2; ++mt)
            afr[mt] = *(const bf16x8*)(xt + (m0 + mt * 16 + col) * PITCH + kb * 32 + quad * 8);
#pragma unroll
        for (int i = 0; i < 4; ++i) {
            int nt = ch * 4 + i;
            bf16x8 bfr = *(const bf16x8*)(Wfr + ((kb * 8 + nt) * 64 + lane) * 8);
            acc[0][i] = __builtin_amdgcn_mfma_f32_16x16x32_bf16(afr[0], bfr, acc[0][i], 0, 0, 0);
            acc[1][i] = __builtin_amdgcn_mfma_f32_16x16x32_bf16(afr[1], bfr, acc[1][i], 0, 0, 0);
        }
    }

    float bb[4];
#pragma unroll
    for (int i = 0; i < 4; ++i) bb[i] = b[(ch * 4 + i) * 16 + col];

    __syncthreads();

#pragma unroll
    for (int mt = 0; mt < 2; ++mt)
#pragma unroll
        for (int rr = 0; rr < 4; ++rr) {
            int row = m0 + mt * 16 + quad * 4 + rr;
            uint2 v;
            v.x = cvtpk(acc[mt][0][rr] + bb[0], acc[mt][1][rr] + bb[1]);
            v.y = cvtpk(acc[mt][2][rr] + bb[2], acc[mt][3][rr] + bb[3]);
            *(uint2*)(xt + (size_t)row * PITCH + col * 8 + ch * 4) = v;
        }
    __syncthreads();

    {
        int row = t >> 2;
        int seg = t & 3;
        if (r0 + row < N) {
            const uint4* lp = (const uint4*)(xt + (size_t)row * PITCH + seg * 32);
            uint4* gp = (uint4*)(out + (size_t)(r0 + row) * 128 + seg * 32);
            uint4 a0 = lp[0], a1 = lp[1], a2 = lp[2], a3 = lp[3];
            gp[0] = a0; gp[1] = a1; gp[2] = a2; gp[3] = a3;
        }
    }
}

// Edge kernel — CONSOLIDATED BEST (r0 form, 99.8us measured): TE=128,
// 512 thr, single tile/block, single dispatch, transient gathers, two
// staging windows, coalesced out stores; + bias-init acc + hoisted b2.
// Session evidence (6 structural variants): edge time == FETCH / ~2.3 TB/s
// (random-256B-row gather path through EA/MALL), invariant across occupancy
// 40-87%, block 256/512, pipelining, grid splits. FETCH's floor at original
// edge order is ~226 MB (feature re-fetch across 8 non-coherent L2s).
// Src-bucketing cuts u-traffic but the required out-permutation costs as
// much as it saves (r6: scattered 4B cross-XCD stores -> 10.9M line
// transfers, 1.39 GB writes). Do NOT reintroduce: multi-tile loops (spill,
// r1/r2), scattered global stores (false sharing, r6), Wf-in-LDS (occupancy,
// r1), grid splits (+10us ramp/drain, r5).
#define TE 128

__global__ __launch_bounds__(512, 6) void edge_kernel(
    const unsigned short* __restrict__ u_f, const unsigned short* __restrict__ i_f,
    const int* __restrict__ src, const int* __restrict__ dst,
    const unsigned short* __restrict__ Wf,
    const float* __restrict__ b1, const float* __restrict__ W2,
    const float* __restrict__ b2, float* __restrict__ out, int E) {
    __shared__ unsigned short xt[TE * PITCH];
    __shared__ float zb[4][2][32];
    int t = threadIdx.x;
    int e0 = blockIdx.x * TE;

    int s = t & 15;
    int el0 = t >> 4;  // 0..31

    int wave = t >> 6;
    int lane = t & 63;
    int col = lane & 15;
    int quad = lane >> 4;
    int wp = wave >> 1;  // wave pair -> edge group
    int ch = wave & 1;   // col half
    int m0 = wp * 32;

    // ---- hoisted invariant weights ----
    float bb[4], ww[4];
#pragma unroll
    for (int i = 0; i < 4; ++i) {
        int n = (ch * 4 + i) * 16 + col;
        bb[i] = b1[n];
        ww[i] = W2[n];
    }
    float b2v = b2[0];

    // window 1: all 8 index loads
    int su[4], sd[4];
#pragma unroll
    for (int pass = 0; pass < 4; ++pass) {
        int ec = min(e0 + pass * 32 + el0, E - 1);
        su[pass] = src[ec];
        sd[pass] = dst[ec];
    }
    // window 2: all 8 feature gathers (transient registers)
    {
        uint4 ug[4], ig[4];
#pragma unroll
        for (int pass = 0; pass < 4; ++pass) {
            ug[pass] = *(const uint4*)(u_f + (size_t)su[pass] * 128 + s * 8);
            ig[pass] = *(const uint4*)(i_f + (size_t)sd[pass] * 128 + s * 8);
        }
#pragma unroll
        for (int pass = 0; pass < 4; ++pass) {
            uint4 a;
            a.x = mix1(ug[pass].x, ig[pass].x);
            a.y = mix1(ug[pass].y, ig[pass].y);
            a.z = mix1(ug[pass].z, ig[pass].z);
            a.w = mix1(ug[pass].w, ig[pass].w);
            *(uint4*)(xt + (pass * 32 + el0) * PITCH + s * 8) = a;
        }
    }
    __syncthreads();

    // ---- MFMA: wave handles 32 edges x 64 cols; acc starts at b1 ----
    f32x4 acc[2][4];
#pragma unroll
    for (int mt = 0; mt < 2; ++mt)
#pragma unroll
        for (int i = 0; i < 4; ++i)
            acc[mt][i] = (f32x4){bb[i], bb[i], bb[i], bb[i]};

#pragma unroll
    for (int kb = 0; kb < 4; ++kb) {
        bf16x8 afr[2];
#pragma unroll
        for (int mt = 0; mt < 2; ++mt)
            afr[mt] = *(const bf16x8*)(xt + (m0 + mt * 16 + col) * PITCH + kb * 32 + quad * 8);
#pragma unroll
        for (int i = 0; i < 4; ++i) {
            int nt = ch * 4 + i;
            bf16x8 bfr = *(const bf16x8*)(Wf + ((kb * 8 + nt) * 64 + lane) * 8);
            acc[0][i] = __builtin_amdgcn_mfma_f32_16x16x32_bf16(afr[0], bfr, acc[0][i], 0, 0, 0);
            acc[1][i] = __builtin_amdgcn_mfma_f32_16x16x32_bf16(afr[1], bfr, acc[1][i], 0, 0, 0);
        }
    }

    // ---- epilogue: leaky + W2 dot, partial over this wave's 64 cols ----
    f32x4 pz[2];
#pragma unroll
    for (int mt = 0; mt < 2; ++mt) pz[mt] = (f32x4){0.f, 0.f, 0.f, 0.f};

#pragma unroll
    for (int i = 0; i < 4; ++i) {
#pragma unroll
        for (int mt = 0; mt < 2; ++mt) {
            f32x4 y = acc[mt][i];
            y = __builtin_elementwise_max(y, y * 0.01f);
            pz[mt] += y * ww[i];
        }
    }
#pragma unroll
    for (int off = 1; off < 16; off <<= 1)
#pragma unroll
        for (int mt = 0; mt < 2; ++mt)
#pragma unroll
            for (int rr = 0; rr < 4; ++rr) pz[mt][rr] += __shfl_xor(pz[mt][rr], off, 64);

    if (col == 0) {
#pragma unroll
        for (int mt = 0; mt < 2; ++mt)
#pragma unroll
            for (int rr = 0; rr < 4; ++rr)
                zb[wp][ch][mt * 16 + quad * 4 + rr] = pz[mt][rr];
    }
    __syncthreads();

    if (t < 128) {
        int g = t >> 5;       // wave pair
        int idx = t & 31;     // edge within pair
        float z = zb[g][0][idx] + zb[g][1][idx] + b2v;
        int e = e0 + g * 32 + idx;
        if (e < E) out[e] = leaky(z);
    }
}

extern "C" void kernel_launch(void* const* d_in, const int* in_sizes, int n_in,
                              void* d_out, int out_size, void* d_ws, size_t ws_size,
                              hipStream_t stream) {
    const float* h_user  = (const float*)d_in[0];
    const float* h_item  = (const float*)d_in[1];
    const int*   src_idx = (const int*)d_in[2];
    const int*   dst_idx = (const int*)d_in[3];
    const float* W_left  = (const float*)d_in[4];
    const float* b_left  = (const float*)d_in[5];
    const float* W_right = (const float*)d_in[6];
    const float* b_right = (const float*)d_in[7];
    const float* W1      = (const float*)d_in[8];
    const float* b1      = (const float*)d_in[9];
    const float* W2      = (const float*)d_in[10];
    const float* b2      = (const float*)d_in[11];
    float* out = (float*)d_out;

    int N_U = in_sizes[0] / 128;
    int N_I = in_sizes[1] / 128;
    int E   = in_sizes[2];

    // Workspace: [Wf 32KB][WLf 32KB][WRf 32KB][pad to 128KB][u_f bf16][i_f bf16]
    unsigned short* Wf  = (unsigned short*)d_ws;
    unsigned short* WLf = Wf + 16384;
    unsigned short* WRf = WLf + 16384;
    unsigned short* u_f = (unsigned short*)((char*)d_ws + 131072);
    unsigned short* i_f = u_f + (size_t)N_U * 128;

    prep<<<384, 128, 0, stream>>>(W_left, W_right, W1, WLf, WRf, Wf);

    int BU = (N_U + 127) / 128;
    int BI = (N_I + 127) / 128;
    node_mfma2<<<BU + BI, 512, 0, stream>>>(h_user, h_item, WLf, WRf, b_left, b_right,
                                            u_f, i_f, N_U, N_I, BU);

    edge_kernel<<<(E + TE - 1) / TE, 512, 0, stream>>>(u_f, i_f, src_idx, dst_idx,
                                                       Wf, b1, W2, b2, out, E);
}